// Round 8
// baseline (49.723 us; speedup 1.0000x reference)
//
#include <hip/hip_runtime.h>

#define NN 1024
#define BB 16
#define NTY 3

typedef float v2f __attribute__((ext_vector_type(2)));

__device__ __forceinline__ v2f pk_fma(v2f a, v2f b, v2f c) {
    v2f d;
    asm("v_pk_fma_f32 %0, %1, %2, %3" : "=v"(d) : "v"(a), "v"(b), "v"(c));
    return d;
}

// s_tbl[ti*3+tj] = (py, lpx, ry, lry):
//   phi  = 2^( py*d + lpx )   py = -p1*log2e        lpx = log2(p0) + p1*p2*log2e
//   rho² = 2^( ry*d + lry )   ry = -2*r1*log2e      lry = 2*(log2(r0) + r1*r2*log2e)
__global__ __launch_bounds__(256) void eam_rows(
    const int* __restrict__ types, const int* __restrict__ n_atoms,
    const float* __restrict__ distances,
    const float* __restrict__ phi_params, const float* __restrict__ rho_params,
    const float* __restrict__ emb_params, float* __restrict__ blk_part)
{
    __shared__ int4   s_types4[NN / 4];
    __shared__ float4 s_tbl[NTY * NTY];
    __shared__ float  s_rowe[8];

    const int tid = threadIdx.x;
    const int b  = blockIdx.y;
    const int bx = blockIdx.x;          // 0..127

    s_types4[tid] = ((const int4*)(types + b * NN))[tid];

    if (tid < NTY * NTY) {
        const int ti = tid / NTY, tj = tid % NTY;
        const int lo = min(ti, tj), hi = max(ti, tj);
        const int pt = lo * (2 * NTY - lo + 1) / 2 + (hi - lo);
        const float p0 = phi_params[pt * 3 + 0];
        const float p1 = phi_params[pt * 3 + 1];
        const float p2 = phi_params[pt * 3 + 2];
        const float r0 = rho_params[pt * 3 + 0];
        const float r1 = rho_params[pt * 3 + 1];
        const float r2 = rho_params[pt * 3 + 2];
        const float LOG2E = 1.44269504088896f;
        s_tbl[tid] = make_float4(
            -p1 * LOG2E, __log2f(p0) + p1 * p2 * LOG2E,
            -2.0f * r1 * LOG2E, 2.0f * (__log2f(r0) + r1 * r2 * LOG2E));
    }
    __syncthreads();

    const int lane = tid & 63;
    const int wave = tid >> 6;
    const int na = n_atoms[b];
    const bool p2 = na > 512;
    const bool p3 = na > 768;
    const int* s_types = (const int*)s_types4;

    const int iA = bx + wave * 256;     // strided rows: balanced tail
    const int iB = iA + 128;
    const bool vA = iA < na;
    const bool vB = iB < na;

    const float4 z4 = make_float4(0.f, 0.f, 0.f, 0.f);
    float4 a0 = z4, a1 = z4, a2 = z4, a3 = z4;
    float4 b0 = z4, b1 = z4, b2 = z4, b3 = z4;
    float dAii = 0.f, dBii = 0.f;
    int tiA = 0, tiB = 0;

    if (vA) {
        tiA = s_types[iA];
        const float4* rA = (const float4*)(distances + ((size_t)(b * NN + iA)) * NN);
        a0 = rA[lane];
        a1 = rA[64 + lane];
        if (p2) a2 = rA[128 + lane];
        if (p3) a3 = rA[192 + lane];
        dAii = ((const float*)rA)[iA];
    }
    if (vB) {
        tiB = s_types[iB];
        const float4* rB = (const float4*)(distances + ((size_t)(b * NN + iB)) * NN);
        b0 = rB[lane];
        b1 = rB[64 + lane];
        if (p2) b2 = rB[128 + lane];
        if (p3) b3 = rB[192 + lane];
        dBii = ((const float*)rB)[iB];
    }

    // hoist params as packed pairs: PY=(py,ry), PL=(lpx,lry) per tj candidate
    const float4 tA0 = s_tbl[tiA * NTY + 0];
    const float4 tA1 = s_tbl[tiA * NTY + 1];
    const float4 tA2 = s_tbl[tiA * NTY + 2];
    const float4 tB0 = s_tbl[tiB * NTY + 0];
    const float4 tB1 = s_tbl[tiB * NTY + 1];
    const float4 tB2 = s_tbl[tiB * NTY + 2];
    const v2f pyA0 = {tA0.x, tA0.z}, plA0 = {tA0.y, tA0.w};
    const v2f pyA1 = {tA1.x, tA1.z}, plA1 = {tA1.y, tA1.w};
    const v2f pyA2 = {tA2.x, tA2.z}, plA2 = {tA2.y, tA2.w};
    const v2f pyB0 = {tB0.x, tB0.z}, plB0 = {tB0.y, tB0.w};
    const v2f pyB1 = {tB1.x, tB1.z}, plB1 = {tB1.y, tB1.w};
    const v2f pyB2 = {tB2.x, tB2.z}, plB2 = {tB2.y, tB2.w};

    v2f accA = {0.f, 0.f};   // (sum_phi, sum_rho²) row A
    v2f accB = {0.f, 0.f};

#define EAM_EL2(E, DA, DB, TT, MASKED, JB)                                    \
    {                                                                         \
        const int tj = (TT);                                                  \
        const bool c1 = tj >= 1, c2 = tj >= 2;                                \
        const v2f ddA = {(DA), (DA)};                                         \
        const v2f ddB = {(DB), (DB)};                                         \
        const v2f pyA = c2 ? pyA2 : (c1 ? pyA1 : pyA0);                       \
        const v2f plA = c2 ? plA2 : (c1 ? plA1 : plA0);                       \
        const v2f gA = pk_fma(pyA, ddA, plA);                                 \
        const v2f pyB = c2 ? pyB2 : (c1 ? pyB1 : pyB0);                       \
        const v2f plB = c2 ? plB2 : (c1 ? plB1 : plB0);                       \
        const v2f gB = pk_fma(pyB, ddB, plB);                                 \
        v2f eA = {__builtin_amdgcn_exp2f(gA.x), __builtin_amdgcn_exp2f(gA.y)};\
        v2f eB = {__builtin_amdgcn_exp2f(gB.x), __builtin_amdgcn_exp2f(gB.y)};\
        if (MASKED) {                                                         \
            const int j = (JB) + (E);                                         \
            if (j >= na) { eA = (v2f){0.f, 0.f}; eB = (v2f){0.f, 0.f}; }      \
        }                                                                     \
        accA += eA;                                                           \
        accB += eB;                                                           \
    }
#define EAM_PASS(P, VA, VB, MASKED)                                           \
    {                                                                         \
        const int c4 = (P) * 64 + lane;                                       \
        const int4 tj4 = s_types4[c4];                                        \
        const int jb = c4 * 4;                                                \
        EAM_EL2(0, (VA).x, (VB).x, tj4.x, MASKED, jb)                         \
        EAM_EL2(1, (VA).y, (VB).y, tj4.y, MASKED, jb)                         \
        EAM_EL2(2, (VA).z, (VB).z, tj4.z, MASKED, jb)                         \
        EAM_EL2(3, (VA).w, (VB).w, tj4.w, MASKED, jb)                         \
    }
    EAM_PASS(0, a0, b0, false)
    EAM_PASS(1, a1, b1, false)
    if (p3) {
        EAM_PASS(2, a2, b2, false)
        EAM_PASS(3, a3, b3, true)
    } else if (p2) {
        EAM_PASS(2, a2, b2, true)
    }
#undef EAM_PASS
#undef EAM_EL2

    float sphA = accA.x, srhA = accA.y, sphB = accB.x, srhB = accB.y;
#pragma unroll
    for (int o = 32; o > 0; o >>= 1) {
        sphA += __shfl_xor(sphA, o, 64);
        srhA += __shfl_xor(srhA, o, 64);
        sphB += __shfl_xor(sphB, o, 64);
        srhB += __shfl_xor(srhB, o, 64);
    }

    if (lane == 0) {
        float eA = 0.f, eB = 0.f;
        if (vA) {
            const v2f pyd = (tiA == 0) ? pyA0 : (tiA == 1) ? pyA1 : pyA2;
            const v2f pld = (tiA == 0) ? plA0 : (tiA == 1) ? plA1 : plA2;
            const float phid = __builtin_amdgcn_exp2f(fmaf(pyd.x, dAii, pld.x));
            const float rhid = __builtin_amdgcn_exp2f(fmaf(pyd.y, dAii, pld.y));
            const float A   = emb_params[tiA * 2 + 0];
            const float off = emb_params[tiA * 2 + 1];
            eA = (sphA - phid) + (-A * sqrtf(fmaxf(srhA - rhid, 1e-30f)) + off);
        }
        if (vB) {
            const v2f pyd = (tiB == 0) ? pyB0 : (tiB == 1) ? pyB1 : pyB2;
            const v2f pld = (tiB == 0) ? plB0 : (tiB == 1) ? plB1 : plB2;
            const float phid = __builtin_amdgcn_exp2f(fmaf(pyd.x, dBii, pld.x));
            const float rhid = __builtin_amdgcn_exp2f(fmaf(pyd.y, dBii, pld.y));
            const float A   = emb_params[tiB * 2 + 0];
            const float off = emb_params[tiB * 2 + 1];
            eB = (sphB - phid) + (-A * sqrtf(fmaxf(srhB - rhid, 1e-30f)) + off);
        }
        s_rowe[wave * 2 + 0] = eA;
        s_rowe[wave * 2 + 1] = eB;
    }
    __syncthreads();

    if (tid == 0) {
        float s = 0.f;
#pragma unroll
        for (int k = 0; k < 8; ++k) s += s_rowe[k];
        blk_part[b * 128 + bx] = s;     // plain store — no atomics, no fences
    }
}

__global__ __launch_bounds__(64) void eam_reduce(
    const float* __restrict__ blk_part, const int* __restrict__ n_atoms,
    float* __restrict__ out)
{
    const int b = blockIdx.x;
    const int lane = threadIdx.x;
    float s = blk_part[b * 128 + lane] + blk_part[b * 128 + 64 + lane];
#pragma unroll
    for (int o = 32; o > 0; o >>= 1) s += __shfl_xor(s, o, 64);
    if (lane == 0) out[b] = s / (float)n_atoms[b];
}

extern "C" void kernel_launch(void* const* d_in, const int* in_sizes, int n_in,
                              void* d_out, int out_size, void* d_ws, size_t ws_size,
                              hipStream_t stream) {
    const int*   types      = (const int*)d_in[0];
    const int*   n_atoms    = (const int*)d_in[1];
    const float* distances  = (const float*)d_in[2];
    // d_in[3] = pair_types: recomputed on the fly, not read
    const float* phi_params = (const float*)d_in[4];
    const float* rho_params = (const float*)d_in[5];
    const float* emb_params = (const float*)d_in[6];

    float* blk_part = (float*)d_ws;   // 16*128 floats = 8 KB

    // ---- DECOMPOSITION PROBE (intentional, reverted next round) ----
    // Triple both kernels (idempotent, deterministic). With baseline
    // ov + t1 + t2 = 20.07 us, this run gives ov + 3*(t1+t2):
    //   t1+t2 = (dur_new - 20.07)/2,  ov = 20.07 - (t1+t2).
    for (int r = 0; r < 3; ++r) {
        eam_rows<<<dim3(128, BB), 256, 0, stream>>>(
            types, n_atoms, distances, phi_params, rho_params, emb_params,
            blk_part);
    }
    for (int r = 0; r < 3; ++r) {
        eam_reduce<<<BB, 64, 0, stream>>>(blk_part, n_atoms, (float*)d_out);
    }
}

// Round 9
// 21.443 us; speedup vs baseline: 2.3188x; 2.3188x over previous
//
#include <hip/hip_runtime.h>

#define NN 1024
#define BB 16
#define NTY 3

typedef float v2f __attribute__((ext_vector_type(2)));

__device__ __forceinline__ v2f pk_fma(v2f a, v2f b, v2f c) {
    v2f d;
    asm("v_pk_fma_f32 %0, %1, %2, %3" : "=v"(d) : "v"(a), "v"(b), "v"(c));
    return d;
}

// Per wave: one row i of one batch b. No LDS, no barriers.
// phi  = 2^( py(tj)*d + pl(tj) ),  rho² = 2^( ry(tj)*d + rl(tj) )
// (py,ry)/(pl,rl) are exact quadratics in tj (interpolating tj=0,1,2).
__global__ __launch_bounds__(256) void eam_rows(
    const int* __restrict__ types, const int* __restrict__ n_atoms,
    const float* __restrict__ distances,
    const float* __restrict__ phi_params, const float* __restrict__ rho_params,
    const float* __restrict__ emb_params, float* __restrict__ row_e)
{
    const int tid  = threadIdx.x;
    const int lane = tid & 63;
    const int wave = tid >> 6;
    const int b    = blockIdx.x;       // 0..15  (batch-major → CU load balance)
    const int bx   = blockIdx.y;       // 0..255
    const int i    = bx + (wave << 8); // this wave's row, strided by 256

    const int na = n_atoms[b];
    const bool valid = i < na;
    const bool p2 = na > 512, p3 = na > 768;

    // row type first (params depend on it) — wave-uniform broadcast load
    const int ti = types[b * NN + i];

    // row distances: issue all loads up front; drain during param build
    const float4* drow = (const float4*)(distances + ((size_t)(b * NN + i)) * NN);
    float4 v0 = {0,0,0,0}, v1 = {0,0,0,0}, v2 = {0,0,0,0}, v3 = {0,0,0,0};
    float dii = 0.f;
    if (valid) {
        v0 = drow[lane];
        v1 = drow[64 + lane];
        if (p2) v2 = drow[128 + lane];
        if (p3) v3 = drow[192 + lane];
        dii = ((const float*)drow)[i];
    }
    const int4* trow = (const int4*)(types + b * NN);  // column types, L1/L2-hot

    // per-tj params -> exponent-domain pairs, then quadratic coefficients
    const float LOG2E = 1.44269504088896f;
    v2f PY[3], PL[3];
#pragma unroll
    for (int tj = 0; tj < NTY; ++tj) {
        const int lo = min(ti, tj), hi = max(ti, tj);
        const int pt = lo * (2 * NTY - lo + 1) / 2 + (hi - lo);
        const float q0 = phi_params[pt * 3 + 0];
        const float q1 = phi_params[pt * 3 + 1];
        const float q2 = phi_params[pt * 3 + 2];
        const float r0 = rho_params[pt * 3 + 0];
        const float r1 = rho_params[pt * 3 + 1];
        const float r2 = rho_params[pt * 3 + 2];
        PY[tj] = (v2f){-q1 * LOG2E, -2.0f * r1 * LOG2E};
        PL[tj] = (v2f){__log2f(q0) + q1 * q2 * LOG2E,
                       2.0f * (__log2f(r0) + r1 * r2 * LOG2E)};
    }
    const v2f aY = 0.5f * (PY[2] - PY[1] - PY[1] + PY[0]);
    const v2f bY = PY[1] - PY[0] - aY;
    const v2f cY = PY[0];
    const v2f aL = 0.5f * (PL[2] - PL[1] - PL[1] + PL[0]);
    const v2f bL = PL[1] - PL[0] - aL;
    const v2f cL = PL[0];

    v2f acc = {0.f, 0.f};   // (sum_phi, sum_rho²)

#define EAM_EL(DD, TJ, MASKED, J)                                             \
    {                                                                         \
        const float tf = (float)(TJ);                                         \
        const v2f tv = {tf, tf};                                              \
        const v2f dv = {(DD), (DD)};                                          \
        const v2f py = pk_fma(pk_fma(aY, tv, bY), tv, cY);                    \
        const v2f pl = pk_fma(pk_fma(aL, tv, bL), tv, cL);                    \
        const v2f g  = pk_fma(py, dv, pl);                                    \
        v2f e = {__builtin_amdgcn_exp2f(g.x), __builtin_amdgcn_exp2f(g.y)};   \
        if (MASKED) { if ((J) >= na) e = (v2f){0.f, 0.f}; }                   \
        acc += e;                                                             \
    }
#define EAM_PASS(P, V, MASKED)                                                \
    {                                                                         \
        const int c4 = (P) * 64 + lane;                                       \
        const int4 tj4 = trow[c4];                                            \
        const int jb = c4 * 4;                                                \
        EAM_EL((V).x, tj4.x, MASKED, jb + 0)                                  \
        EAM_EL((V).y, tj4.y, MASKED, jb + 1)                                  \
        EAM_EL((V).z, tj4.z, MASKED, jb + 2)                                  \
        EAM_EL((V).w, tj4.w, MASKED, jb + 3)                                  \
    }
    EAM_PASS(0, v0, false)
    EAM_PASS(1, v1, false)
    if (p3) {
        EAM_PASS(2, v2, false)
        EAM_PASS(3, v3, true)
    } else if (p2) {
        EAM_PASS(2, v2, true)
    }
#undef EAM_PASS
#undef EAM_EL

    float sph = acc.x, srh = acc.y;
#pragma unroll
    for (int o = 32; o > 0; o >>= 1) {
        sph += __shfl_xor(sph, o, 64);
        srh += __shfl_xor(srh, o, 64);
    }

    float rowE = 0.f;
    if (valid) {
        // subtract the diagonal (j == i) contribution
        const float tf = (float)ti;
        const v2f tv = {tf, tf};
        const v2f dv = {dii, dii};
        const v2f py = pk_fma(pk_fma(aY, tv, bY), tv, cY);
        const v2f pl = pk_fma(pk_fma(aL, tv, bL), tv, cL);
        const v2f g  = pk_fma(py, dv, pl);
        const float phid = __builtin_amdgcn_exp2f(g.x);
        const float rhid = __builtin_amdgcn_exp2f(g.y);
        const float A   = emb_params[ti * 2 + 0];
        const float off = emb_params[ti * 2 + 1];
        rowE = (sph - phid) +
               (-A * sqrtf(fmaxf(srh - rhid, 1e-30f)) + off);
    }
    if (lane == 0) row_e[b * NN + i] = rowE;   // every (b,i) written exactly once
}

__global__ __launch_bounds__(64) void eam_reduce(
    const float* __restrict__ row_e, const int* __restrict__ n_atoms,
    float* __restrict__ out)
{
    const int b = blockIdx.x;
    const int lane = threadIdx.x;
    const float4* p = (const float4*)(row_e + b * NN);
    float s = 0.f;
#pragma unroll
    for (int k = 0; k < 4; ++k) {
        const float4 v = p[lane + 64 * k];
        s += v.x + v.y + v.z + v.w;
    }
#pragma unroll
    for (int o = 32; o > 0; o >>= 1) s += __shfl_xor(s, o, 64);
    if (lane == 0) out[b] = s / (float)n_atoms[b];
}

extern "C" void kernel_launch(void* const* d_in, const int* in_sizes, int n_in,
                              void* d_out, int out_size, void* d_ws, size_t ws_size,
                              hipStream_t stream) {
    const int*   types      = (const int*)d_in[0];
    const int*   n_atoms    = (const int*)d_in[1];
    const float* distances  = (const float*)d_in[2];
    // d_in[3] = pair_types: recomputed on the fly, not read
    const float* phi_params = (const float*)d_in[4];
    const float* rho_params = (const float*)d_in[5];
    const float* emb_params = (const float*)d_in[6];

    float* row_e = (float*)d_ws;   // 16*1024 floats = 64 KB

    eam_rows<<<dim3(BB, 256), 256, 0, stream>>>(
        types, n_atoms, distances, phi_params, rho_params, emb_params, row_e);
    eam_reduce<<<BB, 64, 0, stream>>>(row_e, n_atoms, (float*)d_out);
}